// Round 4
// baseline (558.511 us; speedup 1.0000x reference)
//
#include <hip/hip_runtime.h>

#define NTAG 128
#define SEQ 512
#define NBATCH 512
#define END_ID 1
#define GB 16          // batches per wave (MFMA N dimension)
#define EMARGIN 4      // renorm headroom bits

typedef _Float16 v8h __attribute__((ext_vector_type(8)));
typedef _Float16 h2v __attribute__((ext_vector_type(2)));
typedef float f32x4 __attribute__((ext_vector_type(4)));
typedef __fp16 fp16x2 __attribute__((ext_vector_type(2)));

#define LOG2E 1.4426950408889634f
#define LN2   0.6931471805599453f

__device__ __forceinline__ uint pack2(float a, float b) {
  fp16x2 h = __builtin_amdgcn_cvt_pkrtz(a, b);
  return __builtin_bit_cast(uint, h);
}
__device__ __forceinline__ float fast_exp2(float x) {
#if __has_builtin(__builtin_amdgcn_exp2f)
  return __builtin_amdgcn_exp2f(x);
#else
  return exp2f(x);
#endif
}
__device__ __forceinline__ float fast_log2(float x) {
#if __has_builtin(__builtin_amdgcn_logf)
  return __builtin_amdgcn_logf(x);
#else
  return log2f(x);
#endif
}
__device__ __forceinline__ uint hmax2u(uint a, uint b) {
#if __has_builtin(__builtin_elementwise_max)
  h2v r = __builtin_elementwise_max(__builtin_bit_cast(h2v, a),
                                    __builtin_bit_cast(h2v, b));
  return __builtin_bit_cast(uint, r);
#else
  h2v x = __builtin_bit_cast(h2v, a), y = __builtin_bit_cast(h2v, b);
  h2v r; r[0] = x[0] > y[0] ? x[0] : y[0]; r[1] = x[1] > y[1] ? x[1] : y[1];
  return __builtin_bit_cast(uint, r);
#endif
}

// ROUND-12: back to the barrier-free IN-WAVE MFMA recurrence (round 10 /
// bench round 2), which is race-free and whose issue floor is ~620 cyc/step
// (32 MFMA x ~19.4 SIMD-cyc), with its two measured defects fixed:
//   (a) x prefetch was effectively depth-1 -> ~300-500 cyc HBM latency
//       exposed on the chain every step. Now: DEPTH-4 ring of named float4[8]
//       buffers (128 VGPRs), refill issued at step start, consumed 4 steps
//       (~2800 cyc) later. No barriers anywhere, so no vmcnt(0) drain can
//       kill the pipeline (that drain is what sank bench rounds 1/3).
//   (b) x streamed to group-max rows for all 16 batches -> 2x over-fetch
//       (69.7 MB vs 36). Now: refill row index clamped to per-batch len.
// Renorm exponent: packed-f16 max (hmax2u) over the 16 packed uints + 2
// shfl_xor, off the critical path (feeds NEXT step's csh only).
// D->B fragment identity, k-enum, and epilogue are verbatim from the
// validated round-2 kernel (absmax 0.0).
__global__ __launch_bounds__(64, 1) void crf_kernel(
    const float* __restrict__ x,      // [B,S,T]
    const int*   __restrict__ tags,   // [B,S]
    const float* __restrict__ mask,   // [B,S]
    const float* __restrict__ trans,  // [T,T]
    float* __restrict__ ws)           // [B]
{
  const int bg = blockIdx.x * GB;     // batch group base
  const int l  = threadIdx.x;         // 0..63
  const int m  = l & 15;              // batch-in-group (B/D col; A row-in-tile)
  const int h  = l >> 4;              // k-group / D row-group

  const int bb = bg + m;              // this lane's batch
  const float* xb   = x    + (size_t)bb * SEQ * NTAG;
  const int*   trow = tags + (size_t)bb * SEQ;

  // ---- len for batch bb ----
  float msum = 0.f;
  {
    const float4* m4 = (const float4*)(mask + (size_t)bb * SEQ);
    #pragma unroll
    for (int k = 0; k < 32; ++k) {
      float4 v = m4[h * 32 + k];
      msum += (v.x + v.y) + (v.z + v.w);
    }
    msum += __shfl_xor(msum, 16);
    msum += __shfl_xor(msum, 32);
  }
  const int len = (int)msum;          // in [1, 509]
  int ml = len;
  #pragma unroll
  for (int off = 1; off < 64; off <<= 1) ml = max(ml, __shfl_xor(ml, off));
  const int maxlen4 = (ml + 3) & ~3;  // multiple of 4 (ring depth)

  // ---- A fragments: E'[j,k] = exp(trans[j,k]), f16; k-enum identical on
  //      the B side (validated: absmax 0.0 in rounds 2-3) ----
  v8h Af[8][4];                       // [mtile][kstep]
  #pragma unroll
  for (int mt = 0; mt < 8; ++mt) {
    const float* rowp = trans + (size_t)(mt * 16 + m) * NTAG;
    #pragma unroll
    for (int ks = 0; ks < 4; ++ks) {
      float4 c0 = *(const float4*)(rowp + ks * 32 + h * 4);
      float4 c1 = *(const float4*)(rowp + ks * 32 + 16 + h * 4);
      v8h a;
      a[0] = (_Float16)fast_exp2(c0.x * LOG2E);
      a[1] = (_Float16)fast_exp2(c0.y * LOG2E);
      a[2] = (_Float16)fast_exp2(c0.z * LOG2E);
      a[3] = (_Float16)fast_exp2(c0.w * LOG2E);
      a[4] = (_Float16)fast_exp2(c1.x * LOG2E);
      a[5] = (_Float16)fast_exp2(c1.y * LOG2E);
      a[6] = (_Float16)fast_exp2(c1.z * LOG2E);
      a[7] = (_Float16)fast_exp2(c1.w * LOG2E);
      Af[mt][ks] = a;
    }
  }

  // ---- state ----
  v8h PkA[4], PkB[4];
  #pragma unroll
  for (int ks = 0; ks < 4; ++ks) {
    v8h z;
    #pragma unroll
    for (int i = 0; i < 8; ++i) z[i] = (_Float16)0.0f;
    PkA[ks] = z; PkB[ks] = z;
  }
  if (h == 0) PkA[0][0] = (_Float16)1.0f;   // p0 = delta(START_ID=0)
  float M = 0.f;
  int eprev = 0;

  // ---- x ring, depth 4 (named buffers, all indices compile-time) ----
  const float4* xrow4 = (const float4*)xb;   // row t: xrow4[t*32 + mt*4 + h]
  float4 xr0[8], xr1[8], xr2[8], xr3[8];
  {
    const int r1 = min(1, len), r2 = min(2, len), r3 = min(3, len);
    #pragma unroll
    for (int mt = 0; mt < 8; ++mt) {
      xr0[mt] = xrow4[(size_t)0  * 32 + mt * 4 + h];
      xr1[mt] = xrow4[(size_t)r1 * 32 + mt * 4 + h];
      xr2[mt] = xrow4[(size_t)r2 * 32 + mt * 4 + h];
      xr3[mt] = xrow4[(size_t)r3 * 32 + mt * 4 + h];
    }
  }

  const f32x4 zero4 = {0.f, 0.f, 0.f, 0.f};

#define BODY(PS, PD, XR, T_)                                                  \
  {                                                                           \
    const int t_ = (T_);                                                      \
    const bool act = (t_ < len);                                              \
    const int rr = min(t_ + 4, len);                                          \
    float4 xc[8];                                                             \
    _Pragma("unroll")                                                         \
    for (int mt = 0; mt < 8; ++mt) xc[mt] = XR[mt];                           \
    _Pragma("unroll")                                                         \
    for (int mt = 0; mt < 8; ++mt)                                            \
      XR[mt] = xrow4[(size_t)rr * 32 + mt * 4 + h];                           \
    const float csh = (float)(eprev + EMARGIN);                               \
    uint pu[8][2];                                                            \
    uint mu = 0u;                                                             \
    _Pragma("unroll")                                                         \
    for (int mt = 0; mt < 8; ++mt) {                                          \
      f32x4 d = __builtin_amdgcn_mfma_f32_16x16x32_f16(Af[mt][0], PS[0], zero4, 0, 0, 0); \
      d = __builtin_amdgcn_mfma_f32_16x16x32_f16(Af[mt][1], PS[1], d, 0, 0, 0); \
      d = __builtin_amdgcn_mfma_f32_16x16x32_f16(Af[mt][2], PS[2], d, 0, 0, 0); \
      d = __builtin_amdgcn_mfma_f32_16x16x32_f16(Af[mt][3], PS[3], d, 0, 0, 0); \
      const float4 xv = xc[mt];                                               \
      const float v0 = d[0] * fast_exp2(fmaf(xv.x, LOG2E, -csh));             \
      const float v1 = d[1] * fast_exp2(fmaf(xv.y, LOG2E, -csh));             \
      const float v2 = d[2] * fast_exp2(fmaf(xv.z, LOG2E, -csh));             \
      const float v3 = d[3] * fast_exp2(fmaf(xv.w, LOG2E, -csh));             \
      const uint u0 = pack2(v0, v1);                                          \
      const uint u1 = pack2(v2, v3);                                          \
      pu[mt][0] = u0; pu[mt][1] = u1;                                         \
      mu = hmax2u(mu, hmax2u(u0, u1));                                        \
    }                                                                         \
    _Pragma("unroll")                                                         \
    for (int ks = 0; ks < 4; ++ks) {                                          \
      uint4 q; q.x = pu[2 * ks][0]; q.y = pu[2 * ks][1];                      \
      q.z = pu[2 * ks + 1][0]; q.w = pu[2 * ks + 1][1];                       \
      const v8h nv = __builtin_bit_cast(v8h, q);                              \
      PD[ks] = act ? nv : PS[ks];                                             \
    }                                                                         \
    mu = hmax2u(mu, (uint)__shfl_xor((int)mu, 16));                           \
    mu = hmax2u(mu, (uint)__shfl_xor((int)mu, 32));                           \
    const h2v mh = __builtin_bit_cast(h2v, mu);                               \
    const float fm = fmaxf((float)mh[0], (float)mh[1]);                       \
    int en = ((__float_as_int(fm) >> 23) & 255) - 127;                        \
    en = en < -30 ? -30 : (en > 30 ? 30 : en);                                \
    M     = act ? (M + csh) : M;                                              \
    eprev = act ? en : eprev;                                                 \
  }

  for (int t = 0; t < maxlen4; t += 4) {
    BODY(PkA, PkB, xr0, t)
    BODY(PkB, PkA, xr1, t + 1)
    BODY(PkA, PkB, xr2, t + 2)
    BODY(PkB, PkA, xr3, t + 3)
  }
#undef BODY
  // maxlen4 is a multiple of 4 -> even body count -> final state in PkA

  // ---- fwd = logsumexp_j(alpha[j] + trans[END][j]); alpha=(M+log2 p)ln2 ----
  const float* tE = trans + (size_t)END_ID * NTAG;
  float vv[4][8];
  float m2 = -3.4e38f;
  #pragma unroll
  for (int ks = 0; ks < 4; ++ks) {
    float4 te0 = *(const float4*)(tE + ks * 32 + h * 4);
    float4 te1 = *(const float4*)(tE + ks * 32 + 16 + h * 4);
    #pragma unroll
    for (int i = 0; i < 8; ++i) {
      const float p  = (float)PkA[ks][i];
      const float te = (i < 4)
          ? ((i & 3) == 0 ? te0.x : (i & 3) == 1 ? te0.y : (i & 3) == 2 ? te0.z : te0.w)
          : ((i & 3) == 0 ? te1.x : (i & 3) == 1 ? te1.y : (i & 3) == 2 ? te1.z : te1.w);
      const float v = (M + fast_log2(p)) * LN2 + te;   // p==0 -> -inf, ok
      vv[ks][i] = v;
      m2 = fmaxf(m2, v);
    }
  }
  m2 = fmaxf(m2, __shfl_xor(m2, 16));
  m2 = fmaxf(m2, __shfl_xor(m2, 32));
  float s = 0.f;
  #pragma unroll
  for (int ks = 0; ks < 4; ++ks)
    #pragma unroll
    for (int i = 0; i < 8; ++i)
      s += fast_exp2((vv[ks][i] - m2) * LOG2E);
  s += __shfl_xor(s, 16);
  s += __shfl_xor(s, 32);
  const float fwd = m2 + fast_log2(s) * LN2;

  // ---- gold score (4 h-lanes per batch, strided) ----
  float g = 0.f;
  for (int i = h; i < len; i += 4) {
    const int tn = trow[i + 1];
    const int tp = trow[i];
    g += xb[(size_t)i * NTAG + tn] + trans[(size_t)tn * NTAG + tp];
  }
  g += __shfl_xor(g, 16);
  g += __shfl_xor(g, 32);

  if (h == 0) {
    const float gold = g + trans[(size_t)END_ID * NTAG + trow[len]];
    ws[bb] = fwd - gold;
  }
}

__global__ void reduce_kernel(const float* __restrict__ ws, float* __restrict__ out) {
  __shared__ float sm[8];
  const int tid = threadIdx.x;   // 512
  float v = ws[tid];
  #pragma unroll
  for (int off = 1; off < 64; off <<= 1) v += __shfl_xor(v, off);
  if ((tid & 63) == 0) sm[tid >> 6] = v;
  __syncthreads();
  if (tid == 0) {
    float s = 0.f;
    #pragma unroll
    for (int w = 0; w < 8; ++w) s += sm[w];
    out[0] = s * (1.0f / 512.0f);
  }
}

extern "C" void kernel_launch(void* const* d_in, const int* in_sizes, int n_in,
                              void* d_out, int out_size, void* d_ws, size_t ws_size,
                              hipStream_t stream) {
  const float* x     = (const float*)d_in[0];
  const int*   tags  = (const int*)d_in[1];
  const float* mask  = (const float*)d_in[2];
  const float* trans = (const float*)d_in[3];
  float*       ws    = (float*)d_ws;

  crf_kernel<<<NBATCH / GB, 64, 0, stream>>>(x, tags, mask, trans, ws);
  reduce_kernel<<<1, 512, 0, stream>>>(ws, (float*)d_out);
}